// Round 4
// baseline (1218.632 us; speedup 1.0000x reference)
//
#include <hip/hip_runtime.h>
#include <hip/hip_bf16.h>
#include <math.h>

// ---------------- problem constants ----------------
#define T_TOK 2048
#define H_DIM 512
#define E_NUM 16
#define TOPK  2
#define I_DIM 2048
#define IS_DIM 1024
#define NROWS (T_TOK * TOPK)   // 4096 routed (token,expert) rows

typedef __attribute__((ext_vector_type(8))) short bf16x8;
typedef __attribute__((ext_vector_type(4))) float f32x4;
typedef unsigned short ushort_t;

static __device__ __forceinline__ unsigned short f2bf(float f) {
  unsigned int u = __float_as_uint(f);
  unsigned int r = (u + 0x7fffu + ((u >> 16) & 1u)) >> 16;   // RNE
  return (unsigned short)r;
}

static __device__ __forceinline__ bf16x8 pack8(float4 a, float4 b) {
  bf16x8 v;
  v[0] = (short)f2bf(a.x); v[1] = (short)f2bf(a.y);
  v[2] = (short)f2bf(a.z); v[3] = (short)f2bf(a.w);
  v[4] = (short)f2bf(b.x); v[5] = (short)f2bf(b.y);
  v[6] = (short)f2bf(b.z); v[7] = (short)f2bf(b.w);
  return v;
}

// ---------------- 0) fp32 -> bf16 conversion (streaming) ----------------
__global__ __launch_bounds__(256) void conv_kernel(const float* __restrict__ s,
                                                   ushort_t* __restrict__ d, int n8) {
  int i = blockIdx.x * 256 + threadIdx.x;
  int stride = gridDim.x * 256;
  for (; i < n8; i += stride) {
    float4 f0 = ((const float4*)s)[(size_t)i * 2];
    float4 f1 = ((const float4*)s)[(size_t)i * 2 + 1];
    ((bf16x8*)d)[i] = pack8(f0, f1);
  }
}

// ---------------- 1) gate: logits -> softmax -> top2 -> counts ----------------
__global__ __launch_bounds__(64) void gate_kernel(
    const float* __restrict__ x, const float* __restrict__ gw,
    int* __restrict__ topk_idx, float* __restrict__ topk_w, int* __restrict__ counts)
{
  int t = blockIdx.x;
  int lane = threadIdx.x;
  __shared__ float xs[H_DIM];
  __shared__ float lg[E_NUM];
  const float4* xr = (const float4*)(x + (size_t)t * H_DIM);
  ((float4*)xs)[lane] = xr[lane];
  ((float4*)xs)[lane + 64] = xr[lane + 64];
  __syncthreads();
  if (lane < E_NUM) {
    const float* w = gw + (size_t)lane * H_DIM;
    float acc = 0.f;
    #pragma unroll 8
    for (int h = 0; h < H_DIM; h++) acc += xs[h] * w[h];
    lg[lane] = acc;
  }
  __syncthreads();
  if (lane == 0) {
    float mx = lg[0];
    #pragma unroll
    for (int e = 1; e < E_NUM; e++) mx = fmaxf(mx, lg[e]);
    float sc[E_NUM];
    float sum = 0.f;
    #pragma unroll
    for (int e = 0; e < E_NUM; e++) { sc[e] = expf(lg[e] - mx); sum += sc[e]; }
    float inv = 1.f / sum;
    float m1 = -1.f, m2 = -1.f; int i1 = 0, i2 = 0;
    #pragma unroll
    for (int e = 0; e < E_NUM; e++) {
      float s = sc[e] * inv;
      if (s > m1)      { m2 = m1; i2 = i1; m1 = s; i1 = e; }
      else if (s > m2) { m2 = s; i2 = e; }
    }
    topk_idx[t * 2] = i1; topk_idx[t * 2 + 1] = i2;
    topk_w[t * 2] = m1;  topk_w[t * 2 + 1] = m2;
    atomicAdd(&counts[i1], 1);
    atomicAdd(&counts[i2], 1);
  }
}

// ---------------- 2) exclusive scan over 16 counts ----------------
__global__ void offsets_kernel(const int* __restrict__ counts,
                               int* __restrict__ offsets, int* __restrict__ cursor)
{
  if (threadIdx.x == 0) {
    int acc = 0;
    #pragma unroll
    for (int e = 0; e < E_NUM; e++) { offsets[e] = acc; acc += counts[e]; }
    offsets[E_NUM] = acc;
  }
  if (threadIdx.x < E_NUM) cursor[threadIdx.x] = 0;
}

// ---------------- 3) scatter tokens into per-expert lists ----------------
__global__ __launch_bounds__(256) void scatter_kernel(
    const int* __restrict__ topk_idx, const float* __restrict__ topk_w,
    const int* __restrict__ offsets, int* __restrict__ cursor,
    int* __restrict__ row_token, float* __restrict__ row_w)
{
  int t = blockIdx.x * 256 + threadIdx.x;
  if (t >= T_TOK) return;
  #pragma unroll
  for (int k = 0; k < TOPK; k++) {
    int e = topk_idx[t * 2 + k];
    int pos = atomicAdd(&cursor[e], 1);
    int row = offsets[e] + pos;
    row_token[row] = t;
    row_w[row] = topk_w[t * 2 + k];
  }
}

// ---------------- 4) GU GEMM, barrier-free direct-fragment ----------------
// BM=64 rows x BN=128 cols per block, 4 waves as 2(m)x2(n), each wave 32x64.
// A and B loaded per-lane 16B directly in MFMA fragment layout. No LDS staging.
__global__ __launch_bounds__(256) void gu4_kernel(
    const ushort_t* __restrict__ xb,                       // [T,512] bf16
    const ushort_t* __restrict__ wg_all,
    const ushort_t* __restrict__ wu_all,                   // [E,Idim,512] bf16
    ushort_t* __restrict__ inter,
    const int* __restrict__ row_token,                     // null -> identity rows
    const int* __restrict__ counts,                        // null -> cnt=total_rows
    const int* __restrict__ offsets,                       // null -> base=0
    int Idim, int total_rows, int maxrt)
{
  int e  = blockIdx.x / maxrt;
  int rt = blockIdx.x % maxrt;
  int cnt = counts ? counts[e] : total_rows;
  int n0 = rt * 64;
  if (n0 >= cnt) return;
  int base = offsets ? offsets[e] : 0;
  int c0 = blockIdx.y * 128;
  const ushort_t* wg = wg_all + (size_t)e * Idim * H_DIM;
  const ushort_t* wu = wu_all + (size_t)e * Idim * H_DIM;

  __shared__ int toks[64];
  int tid = threadIdx.x;
  if (tid < 64) {
    int r = n0 + tid; if (r >= cnt) r = cnt - 1;
    toks[tid] = row_token ? row_token[base + r] : (base + r);
  }
  __syncthreads();

  int wid = tid >> 6, lane = tid & 63;
  int wm = wid >> 1, wn = wid & 1;
  int fr = lane & 15, g = lane >> 4;

  const ushort_t* aptr[2];
  #pragma unroll
  for (int mi = 0; mi < 2; mi++)
    aptr[mi] = xb + (size_t)toks[wm * 32 + mi * 16 + fr] * H_DIM + g * 8;
  const ushort_t* bgptr[4];
  const ushort_t* buptr[4];
  #pragma unroll
  for (int ni = 0; ni < 4; ni++) {
    int col = c0 + wn * 64 + ni * 16 + fr;
    bgptr[ni] = wg + (size_t)col * H_DIM + g * 8;
    buptr[ni] = wu + (size_t)col * H_DIM + g * 8;
  }

  f32x4 accg[2][4] = {}, accu[2][4] = {};

  #pragma unroll 2
  for (int kk = 0; kk < H_DIM / 32; kk++) {
    int ko = kk * 32;
    bf16x8 a[2], bg[4], bu[4];
    #pragma unroll
    for (int mi = 0; mi < 2; mi++) a[mi] = *(const bf16x8*)(aptr[mi] + ko);
    #pragma unroll
    for (int ni = 0; ni < 4; ni++) {
      bg[ni] = *(const bf16x8*)(bgptr[ni] + ko);
      bu[ni] = *(const bf16x8*)(buptr[ni] + ko);
    }
    #pragma unroll
    for (int mi = 0; mi < 2; mi++) {
      #pragma unroll
      for (int ni = 0; ni < 4; ni++) {
        accg[mi][ni] = __builtin_amdgcn_mfma_f32_16x16x32_bf16(a[mi], bg[ni], accg[mi][ni], 0, 0, 0);
        accu[mi][ni] = __builtin_amdgcn_mfma_f32_16x16x32_bf16(a[mi], bu[ni], accu[mi][ni], 0, 0, 0);
      }
    }
  }

  // epilogue: silu(g)*u -> bf16 inter
  #pragma unroll
  for (int mi = 0; mi < 2; mi++) {
    #pragma unroll
    for (int j = 0; j < 4; j++) {
      int r = wm * 32 + mi * 16 + g * 4 + j;
      if (n0 + r < cnt) {
        size_t orow = (size_t)(base + n0 + r) * Idim;
        #pragma unroll
        for (int ni = 0; ni < 4; ni++) {
          int col = c0 + wn * 64 + ni * 16 + fr;
          float gg = accg[mi][ni][j], uu = accu[mi][ni][j];
          float s = (gg / (1.f + expf(-gg))) * uu;
          inter[orow + col] = f2bf(s);
        }
      }
    }
  }
}

// ---------------- 5) down GEMM, barrier-free direct-fragment ----------------
// BM=64 x BN=64, 4 waves as 2x2, each wave 32x32. K = Idim (2048) or IS (1024).
__global__ __launch_bounds__(256) void down4_kernel(
    const ushort_t* __restrict__ inter,                    // [rows,Kdim] bf16
    const ushort_t* __restrict__ wd_all,                   // [E,H,Kdim] bf16
    float* __restrict__ outp,
    const int* __restrict__ row_token,                     // null -> identity rows
    const float* __restrict__ row_w,                       // null -> store path
    const int* __restrict__ counts, const int* __restrict__ offsets,
    int Kdim, int total_rows, int maxrt)
{
  int e  = blockIdx.x / maxrt;
  int rt = blockIdx.x % maxrt;
  int cnt = counts ? counts[e] : total_rows;
  int n0 = rt * 64;
  if (n0 >= cnt) return;
  int base = offsets ? offsets[e] : 0;
  int c0 = blockIdx.y * 64;
  const ushort_t* wd = wd_all + (size_t)e * H_DIM * Kdim;

  __shared__ int   toks[64];
  __shared__ float rws[64];
  int tid = threadIdx.x;
  if (tid < 64) {
    int r = n0 + tid;
    if (r < cnt) {
      int row = base + r;
      toks[tid] = row_token ? row_token[row] : row;
      rws[tid]  = row_w ? row_w[row] : 1.f;
    } else { toks[tid] = 0; rws[tid] = 0.f; }
  }
  __syncthreads();

  int wid = tid >> 6, lane = tid & 63;
  int wm = wid >> 1, wn = wid & 1;
  int fr = lane & 15, g = lane >> 4;

  const ushort_t* aptr[2];
  #pragma unroll
  for (int mi = 0; mi < 2; mi++) {
    int r = n0 + wm * 32 + mi * 16 + fr; if (r >= cnt) r = cnt - 1;
    aptr[mi] = inter + (size_t)(base + r) * Kdim + g * 8;
  }
  const ushort_t* bptr[2];
  #pragma unroll
  for (int ni = 0; ni < 2; ni++) {
    int col = c0 + wn * 32 + ni * 16 + fr;
    bptr[ni] = wd + (size_t)col * Kdim + g * 8;
  }

  f32x4 acc[2][2] = {};

  #pragma unroll 4
  for (int kk = 0; kk < Kdim / 32; kk++) {
    int ko = kk * 32;
    bf16x8 a[2], b[2];
    #pragma unroll
    for (int mi = 0; mi < 2; mi++) a[mi] = *(const bf16x8*)(aptr[mi] + ko);
    #pragma unroll
    for (int ni = 0; ni < 2; ni++) b[ni] = *(const bf16x8*)(bptr[ni] + ko);
    #pragma unroll
    for (int mi = 0; mi < 2; mi++)
      #pragma unroll
      for (int ni = 0; ni < 2; ni++)
        acc[mi][ni] = __builtin_amdgcn_mfma_f32_16x16x32_bf16(a[mi], b[ni], acc[mi][ni], 0, 0, 0);
  }

  #pragma unroll
  for (int mi = 0; mi < 2; mi++) {
    #pragma unroll
    for (int j = 0; j < 4; j++) {
      int r = wm * 32 + mi * 16 + g * 4 + j;
      if (n0 + r < cnt) {
        int tk = toks[r];
        float rw = rws[r];
        #pragma unroll
        for (int ni = 0; ni < 2; ni++) {
          int col = c0 + wn * 32 + ni * 16 + fr;
          float v = acc[mi][ni][j];
          if (row_w) atomicAdd(&outp[(size_t)tk * H_DIM + col], v * rw);
          else       outp[(size_t)tk * H_DIM + col] = v;
        }
      }
    }
  }
}

// ---------------- launch ----------------
extern "C" void kernel_launch(void* const* d_in, const int* in_sizes, int n_in,
                              void* d_out, int out_size, void* d_ws, size_t ws_size,
                              hipStream_t stream) {
  const float* x       = (const float*)d_in[0];
  const float* gate_w  = (const float*)d_in[1];
  const float* w_gate  = (const float*)d_in[2];
  const float* w_up    = (const float*)d_in[3];
  const float* w_down  = (const float*)d_in[4];
  const float* sw_gate = (const float*)d_in[5];
  const float* sw_up   = (const float*)d_in[6];
  const float* sw_down = (const float*)d_in[7];
  float* out = (float*)d_out;

  char* ws = (char*)d_ws;
  int*   counts    = (int*)ws;                    // 16 ints
  int*   cursor    = (int*)(ws + 64);             // 16 ints
  int*   offsets   = (int*)(ws + 128);            // 17 ints
  int*   topk_idx  = (int*)(ws + 256);            // 4096 ints
  float* topk_w    = (float*)(ws + 16640);        // 4096 f32
  int*   row_token = (int*)(ws + 33024);          // 4096 ints
  float* row_w     = (float*)(ws + 49408);        // 4096 f32
  size_t off = 65792;
  ushort_t* xb   = (ushort_t*)(ws + off); off += (size_t)T_TOK * H_DIM * 2;         // 2 MiB
  ushort_t* wgb  = (ushort_t*)(ws + off); off += (size_t)E_NUM * I_DIM * H_DIM * 2; // 32 MiB
  ushort_t* wub  = (ushort_t*)(ws + off); off += (size_t)E_NUM * I_DIM * H_DIM * 2; // 32 MiB
  ushort_t* wdb  = (ushort_t*)(ws + off); off += (size_t)E_NUM * H_DIM * I_DIM * 2; // 32 MiB
  ushort_t* swgb = (ushort_t*)(ws + off); off += (size_t)IS_DIM * H_DIM * 2;        // 1 MiB
  ushort_t* swub = (ushort_t*)(ws + off); off += (size_t)IS_DIM * H_DIM * 2;        // 1 MiB
  ushort_t* swdb = (ushort_t*)(ws + off); off += (size_t)H_DIM * IS_DIM * 2;        // 1 MiB
  ushort_t* inter_r = (ushort_t*)(ws + off); off += (size_t)NROWS * I_DIM * 2;      // 16 MiB
  ushort_t* inter_s = (ushort_t*)(ws + off); off += (size_t)T_TOK * IS_DIM * 2;     // 4 MiB

  hipMemsetAsync(counts, 0, 64, stream);
  gate_kernel<<<T_TOK, 64, 0, stream>>>(x, gate_w, topk_idx, topk_w, counts);
  offsets_kernel<<<1, 64, 0, stream>>>(counts, offsets, cursor);
  scatter_kernel<<<(T_TOK + 255) / 256, 256, 0, stream>>>(topk_idx, topk_w, offsets, cursor,
                                                          row_token, row_w);
  // fp32 -> bf16 conversions
  conv_kernel<<<512, 256, 0, stream>>>(x, xb, T_TOK * H_DIM / 8);
  conv_kernel<<<4096, 256, 0, stream>>>(w_gate, wgb, E_NUM * I_DIM * H_DIM / 8);
  conv_kernel<<<4096, 256, 0, stream>>>(w_up, wub, E_NUM * I_DIM * H_DIM / 8);
  conv_kernel<<<4096, 256, 0, stream>>>(w_down, wdb, E_NUM * H_DIM * I_DIM / 8);
  conv_kernel<<<256, 256, 0, stream>>>(sw_gate, swgb, IS_DIM * H_DIM / 8);
  conv_kernel<<<256, 256, 0, stream>>>(sw_up, swub, IS_DIM * H_DIM / 8);
  conv_kernel<<<256, 256, 0, stream>>>(sw_down, swdb, H_DIM * IS_DIM / 8);

  // routed GU: BM=64 (worst 32 row-tiles), BN=128 (16 col-tiles)
  gu4_kernel<<<dim3(E_NUM * 32, I_DIM / 128), 256, 0, stream>>>(
      xb, wgb, wub, inter_r, row_token, counts, offsets, I_DIM, NROWS, 32);
  // shared GU: dense 2048 rows
  gu4_kernel<<<dim3(32, IS_DIM / 128), 256, 0, stream>>>(
      xb, swgb, swub, inter_s, nullptr, nullptr, nullptr, IS_DIM, T_TOK, 32);
  // shared down first (plain stores initialize out fully)
  down4_kernel<<<dim3(32, H_DIM / 64), 256, 0, stream>>>(
      inter_s, swdb, out, nullptr, nullptr, nullptr, nullptr, IS_DIM, T_TOK, 32);
  // routed down: weighted atomic accumulation into out
  down4_kernel<<<dim3(E_NUM * 32, H_DIM / 64), 256, 0, stream>>>(
      inter_r, wdb, out, row_token, row_w, counts, offsets, I_DIM, NROWS, 32);
}

// Round 5
// 368.601 us; speedup vs baseline: 3.3061x; 3.3061x over previous
//
#include <hip/hip_runtime.h>
#include <hip/hip_bf16.h>
#include <math.h>

// ---------------- problem constants ----------------
#define T_TOK 2048
#define H_DIM 512
#define E_NUM 16
#define TOPK  2
#define I_DIM 2048
#define IS_DIM 1024
#define NROWS (T_TOK * TOPK)   // 4096 routed (token,expert) rows

typedef __attribute__((ext_vector_type(8))) short bf16x8;
typedef __attribute__((ext_vector_type(4))) float f32x4;
typedef unsigned short ushort_t;

static __device__ __forceinline__ unsigned short f2bf(float f) {
  unsigned int u = __float_as_uint(f);
  unsigned int r = (u + 0x7fffu + ((u >> 16) & 1u)) >> 16;   // RNE
  return (unsigned short)r;
}

static __device__ __forceinline__ bf16x8 pack8(float4 a, float4 b) {
  bf16x8 v;
  v[0] = (short)f2bf(a.x); v[1] = (short)f2bf(a.y);
  v[2] = (short)f2bf(a.z); v[3] = (short)f2bf(a.w);
  v[4] = (short)f2bf(b.x); v[5] = (short)f2bf(b.y);
  v[6] = (short)f2bf(b.z); v[7] = (short)f2bf(b.w);
  return v;
}

// ---------------- 0a) x: fp32 -> bf16 row-major ----------------
__global__ __launch_bounds__(256) void conv_kernel(const float* __restrict__ s,
                                                   ushort_t* __restrict__ d, int n8) {
  int i = blockIdx.x * 256 + threadIdx.x;
  int stride = gridDim.x * 256;
  for (; i < n8; i += stride) {
    float4 f0 = ((const float4*)s)[(size_t)i * 2];
    float4 f1 = ((const float4*)s)[(size_t)i * 2 + 1];
    ((bf16x8*)d)[i] = pack8(f0, f1);
  }
}

// ---------------- 0b) weights: fp32 row-major -> bf16 FRAGMENT-MAJOR --------
// out bf16x8 chunk i: lane l = i&63, frag fi = i>>6, kk = fi & (KC-1),
// rg = fi >> LKC. Reads w[rg*16 + (l&15)][kk*32 + (l>>4)*8 .. +8].
// A wave's B-fragment load in the GEMM is then ONE contiguous 1KB read.
template <int LKC>
__global__ __launch_bounds__(256) void permw_kernel(const float* __restrict__ s,
                                                    ushort_t* __restrict__ d,
                                                    int n8, int K) {
  const int KC = 1 << LKC;
  int i = blockIdx.x * 256 + threadIdx.x;
  int stride = gridDim.x * 256;
  for (; i < n8; i += stride) {
    int l  = i & 63;
    int fi = i >> 6;
    int kk = fi & (KC - 1);
    int rg = fi >> LKC;
    int row = rg * 16 + (l & 15);
    int ke  = kk * 32 + (l >> 4) * 8;
    const float* p = s + (size_t)row * K + ke;
    float4 f0 = *(const float4*)p;
    float4 f1 = *(const float4*)(p + 4);
    ((bf16x8*)d)[i] = pack8(f0, f1);
  }
}

// ---------------- 1) gate: logits -> softmax -> top2 -> counts ----------------
__global__ __launch_bounds__(64) void gate_kernel(
    const float* __restrict__ x, const float* __restrict__ gw,
    int* __restrict__ topk_idx, float* __restrict__ topk_w, int* __restrict__ counts)
{
  int t = blockIdx.x;
  int lane = threadIdx.x;
  __shared__ float xs[H_DIM];
  __shared__ float lg[E_NUM];
  const float4* xr = (const float4*)(x + (size_t)t * H_DIM);
  ((float4*)xs)[lane] = xr[lane];
  ((float4*)xs)[lane + 64] = xr[lane + 64];
  __syncthreads();
  if (lane < E_NUM) {
    const float* w = gw + (size_t)lane * H_DIM;
    float acc = 0.f;
    #pragma unroll 8
    for (int h = 0; h < H_DIM; h++) acc += xs[h] * w[h];
    lg[lane] = acc;
  }
  __syncthreads();
  if (lane == 0) {
    float mx = lg[0];
    #pragma unroll
    for (int e = 1; e < E_NUM; e++) mx = fmaxf(mx, lg[e]);
    float sc[E_NUM];
    float sum = 0.f;
    #pragma unroll
    for (int e = 0; e < E_NUM; e++) { sc[e] = expf(lg[e] - mx); sum += sc[e]; }
    float inv = 1.f / sum;
    float m1 = -1.f, m2 = -1.f; int i1 = 0, i2 = 0;
    #pragma unroll
    for (int e = 0; e < E_NUM; e++) {
      float s = sc[e] * inv;
      if (s > m1)      { m2 = m1; i2 = i1; m1 = s; i1 = e; }
      else if (s > m2) { m2 = s; i2 = e; }
    }
    topk_idx[t * 2] = i1; topk_idx[t * 2 + 1] = i2;
    topk_w[t * 2] = m1;  topk_w[t * 2 + 1] = m2;
    atomicAdd(&counts[i1], 1);
    atomicAdd(&counts[i2], 1);
  }
}

// ---------------- 2) exclusive scan over 16 counts ----------------
__global__ void offsets_kernel(const int* __restrict__ counts,
                               int* __restrict__ offsets, int* __restrict__ cursor)
{
  if (threadIdx.x == 0) {
    int acc = 0;
    #pragma unroll
    for (int e = 0; e < E_NUM; e++) { offsets[e] = acc; acc += counts[e]; }
    offsets[E_NUM] = acc;
  }
  if (threadIdx.x < E_NUM) cursor[threadIdx.x] = 0;
}

// ---------------- 3) scatter tokens into per-expert lists ----------------
__global__ __launch_bounds__(256) void scatter_kernel(
    const int* __restrict__ topk_idx, const float* __restrict__ topk_w,
    const int* __restrict__ offsets, int* __restrict__ cursor,
    int* __restrict__ row_token, float* __restrict__ row_w)
{
  int t = blockIdx.x * 256 + threadIdx.x;
  if (t >= T_TOK) return;
  #pragma unroll
  for (int k = 0; k < TOPK; k++) {
    int e = topk_idx[t * 2 + k];
    int pos = atomicAdd(&cursor[e], 1);
    int row = offsets[e] + pos;
    row_token[row] = t;
    row_w[row] = topk_w[t * 2 + k];
  }
}

// ---------------- 4) GU GEMM: wave-autonomous, fragment-major B ----------------
// Block = 4 waves sharing 64 rows; wave w owns cols cb*64 + w*16 .. +15.
// grid.x = E * nCB (nCB = Idim/64, lCB = log2), grid.y = row-chunk (stride RC*64).
// No LDS, no barriers. B loads are contiguous 1KB/wave; A is an L2-resident gather.
__global__ __launch_bounds__(256) void gu5_kernel(
    const ushort_t* __restrict__ xb,                       // [T,512] bf16 row-major
    const ushort_t* __restrict__ wgf,                      // fragment-major bf16
    const ushort_t* __restrict__ wuf,
    ushort_t* __restrict__ inter,
    const int* __restrict__ row_token,                     // null -> identity rows
    const int* __restrict__ counts,                        // null -> cnt=total_rows
    const int* __restrict__ offsets,                       // null -> base=0
    int Idim, int total_rows, int lCB, int RC)
{
  int bx = blockIdx.x;
  int e  = bx >> lCB;
  int cb = bx & ((1 << lCB) - 1);
  int cnt  = counts ? counts[e] : total_rows;
  int base = offsets ? offsets[e] : 0;

  int tid = threadIdx.x, w = tid >> 6, lane = tid & 63;
  int fr = lane & 15, g = lane >> 4;
  const int KC = H_DIM / 32;   // 16

  size_t rgB = (size_t)e * (Idim >> 4) + (cb << 2) + w;    // 16-col group index
  const bf16x8* bgp = (const bf16x8*)wgf + rgB * KC * 64 + lane;
  const bf16x8* bup = (const bf16x8*)wuf + rgB * KC * 64 + lane;
  int c0 = (cb << 6) + (w << 4);

  for (int n0 = blockIdx.y * 64; n0 < cnt; n0 += RC * 64) {
    const ushort_t* ap[4];
    #pragma unroll
    for (int mi = 0; mi < 4; mi++) {
      int r = n0 + mi * 16 + fr; if (r >= cnt) r = cnt - 1;
      int t = row_token ? row_token[base + r] : (base + r);
      ap[mi] = xb + (size_t)t * H_DIM + g * 8;
    }

    f32x4 accg[4] = {}, accu[4] = {};
    #pragma unroll 2
    for (int kk = 0; kk < KC; kk++) {
      bf16x8 bg = bgp[(size_t)kk * 64];
      bf16x8 bu = bup[(size_t)kk * 64];
      bf16x8 a[4];
      #pragma unroll
      for (int mi = 0; mi < 4; mi++) a[mi] = *(const bf16x8*)(ap[mi] + kk * 32);
      #pragma unroll
      for (int mi = 0; mi < 4; mi++) {
        accg[mi] = __builtin_amdgcn_mfma_f32_16x16x32_bf16(a[mi], bg, accg[mi], 0, 0, 0);
        accu[mi] = __builtin_amdgcn_mfma_f32_16x16x32_bf16(a[mi], bu, accu[mi], 0, 0, 0);
      }
    }

    #pragma unroll
    for (int mi = 0; mi < 4; mi++) {
      #pragma unroll
      for (int j = 0; j < 4; j++) {
        int r = n0 + mi * 16 + g * 4 + j;
        if (r < cnt) {
          float gg = accg[mi][j], uu = accu[mi][j];
          float s = (gg / (1.f + expf(-gg))) * uu;
          inter[(size_t)(base + r) * Idim + c0 + fr] = f2bf(s);
        }
      }
    }
  }
}

// ---------------- 5) down GEMM: wave-autonomous, fragment-major B ----------------
// Block = 4 waves sharing 64 rows; wave owns 16 output cols. K = Idim or IS.
__global__ __launch_bounds__(256) void down5_kernel(
    const ushort_t* __restrict__ inter,                    // [rows,Kdim] bf16 row-major
    const ushort_t* __restrict__ wdf,                      // fragment-major bf16
    float* __restrict__ outp,
    const int* __restrict__ row_token,                     // null -> identity rows
    const float* __restrict__ row_w,                       // null -> store path
    const int* __restrict__ counts, const int* __restrict__ offsets,
    int Kdim, int KC, int total_rows, int lCB, int RC)
{
  int bx = blockIdx.x;
  int e  = bx >> lCB;
  int cb = bx & ((1 << lCB) - 1);
  int cnt  = counts ? counts[e] : total_rows;
  int base = offsets ? offsets[e] : 0;

  int tid = threadIdx.x, w = tid >> 6, lane = tid & 63;
  int fr = lane & 15, g = lane >> 4;

  size_t rgB = (size_t)e * (H_DIM >> 4) + (cb << 2) + w;
  const bf16x8* bp = (const bf16x8*)wdf + rgB * KC * 64 + lane;
  int c0 = (cb << 6) + (w << 4);

  for (int n0 = blockIdx.y * 64; n0 < cnt; n0 += RC * 64) {
    const ushort_t* ap[4];
    #pragma unroll
    for (int mi = 0; mi < 4; mi++) {
      int r = n0 + mi * 16 + fr; if (r >= cnt) r = cnt - 1;
      ap[mi] = inter + (size_t)(base + r) * Kdim + g * 8;
    }

    f32x4 acc[4] = {};
    #pragma unroll 2
    for (int kk = 0; kk < KC; kk++) {
      bf16x8 b = bp[(size_t)kk * 64];
      bf16x8 a[4];
      #pragma unroll
      for (int mi = 0; mi < 4; mi++) a[mi] = *(const bf16x8*)(ap[mi] + kk * 32);
      #pragma unroll
      for (int mi = 0; mi < 4; mi++)
        acc[mi] = __builtin_amdgcn_mfma_f32_16x16x32_bf16(a[mi], b, acc[mi], 0, 0, 0);
    }

    #pragma unroll
    for (int mi = 0; mi < 4; mi++) {
      #pragma unroll
      for (int j = 0; j < 4; j++) {
        int r = n0 + mi * 16 + g * 4 + j;
        if (r < cnt) {
          int grow = base + r;
          int tk = row_token ? row_token[grow] : grow;
          float v = acc[mi][j];
          int col = c0 + fr;
          if (row_w) atomicAdd(&outp[(size_t)tk * H_DIM + col], v * row_w[grow]);
          else       outp[(size_t)tk * H_DIM + col] = v;
        }
      }
    }
  }
}

// ---------------- launch ----------------
extern "C" void kernel_launch(void* const* d_in, const int* in_sizes, int n_in,
                              void* d_out, int out_size, void* d_ws, size_t ws_size,
                              hipStream_t stream) {
  const float* x       = (const float*)d_in[0];
  const float* gate_w  = (const float*)d_in[1];
  const float* w_gate  = (const float*)d_in[2];
  const float* w_up    = (const float*)d_in[3];
  const float* w_down  = (const float*)d_in[4];
  const float* sw_gate = (const float*)d_in[5];
  const float* sw_up   = (const float*)d_in[6];
  const float* sw_down = (const float*)d_in[7];
  float* out = (float*)d_out;

  char* ws = (char*)d_ws;
  int*   counts    = (int*)ws;                    // 16 ints
  int*   cursor    = (int*)(ws + 64);             // 16 ints
  int*   offsets   = (int*)(ws + 128);            // 17 ints
  int*   topk_idx  = (int*)(ws + 256);            // 4096 ints
  float* topk_w    = (float*)(ws + 16640);        // 4096 f32
  int*   row_token = (int*)(ws + 33024);          // 4096 ints
  float* row_w     = (float*)(ws + 49408);        // 4096 f32
  size_t off = 65792;
  ushort_t* xb   = (ushort_t*)(ws + off); off += (size_t)T_TOK * H_DIM * 2;         // 2 MiB
  ushort_t* wgf  = (ushort_t*)(ws + off); off += (size_t)E_NUM * I_DIM * H_DIM * 2; // 32 MiB
  ushort_t* wuf  = (ushort_t*)(ws + off); off += (size_t)E_NUM * I_DIM * H_DIM * 2; // 32 MiB
  ushort_t* wdf  = (ushort_t*)(ws + off); off += (size_t)E_NUM * H_DIM * I_DIM * 2; // 32 MiB
  ushort_t* swgf = (ushort_t*)(ws + off); off += (size_t)IS_DIM * H_DIM * 2;        // 1 MiB
  ushort_t* swuf = (ushort_t*)(ws + off); off += (size_t)IS_DIM * H_DIM * 2;        // 1 MiB
  ushort_t* swdf = (ushort_t*)(ws + off); off += (size_t)H_DIM * IS_DIM * 2;        // 1 MiB
  ushort_t* inter_r = (ushort_t*)(ws + off); off += (size_t)NROWS * I_DIM * 2;      // 16 MiB
  ushort_t* inter_s = (ushort_t*)(ws + off); off += (size_t)T_TOK * IS_DIM * 2;     // 4 MiB

  hipMemsetAsync(counts, 0, 64, stream);
  gate_kernel<<<T_TOK, 64, 0, stream>>>(x, gate_w, topk_idx, topk_w, counts);
  offsets_kernel<<<1, 64, 0, stream>>>(counts, offsets, cursor);
  scatter_kernel<<<(T_TOK + 255) / 256, 256, 0, stream>>>(topk_idx, topk_w, offsets, cursor,
                                                          row_token, row_w);
  // x: row-major bf16
  conv_kernel<<<512, 256, 0, stream>>>(x, xb, T_TOK * H_DIM / 8);
  // weights: fragment-major bf16. K=512 -> KC=16 (LKC=4); K=2048 -> KC=64 (LKC=6);
  // K=1024 -> KC=32 (LKC=5).
  permw_kernel<4><<<4096, 256, 0, stream>>>(w_gate, wgf, E_NUM * I_DIM * H_DIM / 8, H_DIM);
  permw_kernel<4><<<4096, 256, 0, stream>>>(w_up,   wuf, E_NUM * I_DIM * H_DIM / 8, H_DIM);
  permw_kernel<6><<<4096, 256, 0, stream>>>(w_down, wdf, E_NUM * H_DIM * I_DIM / 8, I_DIM);
  permw_kernel<4><<<256, 256, 0, stream>>>(sw_gate, swgf, IS_DIM * H_DIM / 8, H_DIM);
  permw_kernel<4><<<256, 256, 0, stream>>>(sw_up,   swuf, IS_DIM * H_DIM / 8, H_DIM);
  permw_kernel<5><<<256, 256, 0, stream>>>(sw_down, swdf, H_DIM * IS_DIM / 8, IS_DIM);

  // routed GU: grid (E * I/64 = 512, RC=4)
  gu5_kernel<<<dim3(E_NUM * (I_DIM / 64), 4), 256, 0, stream>>>(
      xb, wgf, wuf, inter_r, row_token, counts, offsets, I_DIM, NROWS, 5, 4);
  // shared GU: grid (IS/64 = 16, 32) — 32 chunks cover 2048 rows exactly
  gu5_kernel<<<dim3(IS_DIM / 64, 32), 256, 0, stream>>>(
      xb, swgf, swuf, inter_s, nullptr, nullptr, nullptr, IS_DIM, T_TOK, 4, 32);
  // shared down first (plain stores initialize out fully): grid (H/64 = 8, 32)
  down5_kernel<<<dim3(H_DIM / 64, 32), 256, 0, stream>>>(
      inter_s, swdf, out, nullptr, nullptr, nullptr, nullptr, IS_DIM, IS_DIM / 32, T_TOK, 3, 32);
  // routed down: weighted atomics: grid (E * H/64 = 128, RC=8)
  down5_kernel<<<dim3(E_NUM * (H_DIM / 64), 8), 256, 0, stream>>>(
      inter_r, wdf, out, row_token, row_w, counts, offsets, I_DIM, I_DIM / 32, NROWS, 3, 8);
}

// Round 6
// 287.814 us; speedup vs baseline: 4.2341x; 1.2807x over previous
//
#include <hip/hip_runtime.h>
#include <hip/hip_bf16.h>
#include <math.h>

// ---------------- problem constants ----------------
#define T_TOK 2048
#define H_DIM 512
#define E_NUM 16
#define TOPK  2
#define I_DIM 2048
#define IS_DIM 1024
#define NROWS (T_TOK * TOPK)   // 4096 routed (token,expert) rows
#define RPMAX 5120             // padded grouped rows upper bound (4096 + 16*63 -> 5120)

typedef __attribute__((ext_vector_type(8))) short bf16x8;
typedef __attribute__((ext_vector_type(4))) float f32x4;
typedef unsigned short ushort_t;

static __device__ __forceinline__ unsigned short f2bf(float f) {
  unsigned int u = __float_as_uint(f);
  unsigned int r = (u + 0x7fffu + ((u >> 16) & 1u)) >> 16;   // RNE
  return (unsigned short)r;
}

static __device__ __forceinline__ bf16x8 pack8(float4 a, float4 b) {
  bf16x8 v;
  v[0] = (short)f2bf(a.x); v[1] = (short)f2bf(a.y);
  v[2] = (short)f2bf(a.z); v[3] = (short)f2bf(a.w);
  v[4] = (short)f2bf(b.x); v[5] = (short)f2bf(b.y);
  v[6] = (short)f2bf(b.z); v[7] = (short)f2bf(b.w);
  return v;
}

// ================= fragment-major (FM) layout =================
// For M[R][K] row-major: chunk c = rg*(K/32) + kk; lane l of chunk holds
// M[rg*16 + (l&15)][kk*32 + (l>>4)*8 .. +8] as one bf16x8 (16B).
// A wave reading one chunk = ONE contiguous 1KB load.

// ---------------- weights fp32 row-major -> FM bf16 ----------------
template <int LKC>
__global__ __launch_bounds__(256) void permw_kernel(const float* __restrict__ s,
                                                    ushort_t* __restrict__ d,
                                                    int n8, int K) {
  const int KC = 1 << LKC;
  int i = blockIdx.x * 256 + threadIdx.x;
  int stride = gridDim.x * 256;
  for (; i < n8; i += stride) {
    int l  = i & 63;
    int fi = i >> 6;
    int kk = fi & (KC - 1);
    int rg = fi >> LKC;
    int row = rg * 16 + (l & 15);
    int ke  = kk * 32 + (l >> 4) * 8;
    const float* p = s + (size_t)row * K + ke;
    float4 f0 = *(const float4*)p;
    float4 f1 = *(const float4*)(p + 4);
    ((bf16x8*)d)[i] = pack8(f0, f1);
  }
}

// ---------------- x fp32 -> FM bf16 with optional token gather ----------------
template <int LKC>
__global__ __launch_bounds__(256) void gatherA_kernel(const float* __restrict__ x,
                                                      const int* __restrict__ row_token,
                                                      ushort_t* __restrict__ d,
                                                      int n8, int K) {
  const int KC = 1 << LKC;
  int i = blockIdx.x * 256 + threadIdx.x;
  int stride = gridDim.x * 256;
  for (; i < n8; i += stride) {
    int l  = i & 63;
    int fi = i >> 6;
    int kk = fi & (KC - 1);
    int rg = fi >> LKC;
    int row = rg * 16 + (l & 15);
    int tok = row_token ? row_token[row] : row;
    bf16x8 v = {};
    if (tok >= 0) {
      const float* p = x + (size_t)tok * K + kk * 32 + (l >> 4) * 8;
      v = pack8(*(const float4*)p, *(const float4*)(p + 4));
    }
    ((bf16x8*)d)[i] = v;
  }
}

// ---------------- 1) gate: logits -> softmax -> top2 -> counts ----------------
__global__ __launch_bounds__(64) void gate_kernel(
    const float* __restrict__ x, const float* __restrict__ gw,
    int* __restrict__ topk_idx, float* __restrict__ topk_w, int* __restrict__ counts)
{
  int t = blockIdx.x;
  int lane = threadIdx.x;
  __shared__ float xs[H_DIM];
  __shared__ float lg[E_NUM];
  const float4* xr = (const float4*)(x + (size_t)t * H_DIM);
  ((float4*)xs)[lane] = xr[lane];
  ((float4*)xs)[lane + 64] = xr[lane + 64];
  __syncthreads();
  if (lane < E_NUM) {
    const float* w = gw + (size_t)lane * H_DIM;
    float acc = 0.f;
    #pragma unroll 8
    for (int h = 0; h < H_DIM; h++) acc += xs[h] * w[h];
    lg[lane] = acc;
  }
  __syncthreads();
  if (lane == 0) {
    float mx = lg[0];
    #pragma unroll
    for (int e = 1; e < E_NUM; e++) mx = fmaxf(mx, lg[e]);
    float sc[E_NUM];
    float sum = 0.f;
    #pragma unroll
    for (int e = 0; e < E_NUM; e++) { sc[e] = expf(lg[e] - mx); sum += sc[e]; }
    float inv = 1.f / sum;
    float m1 = -1.f, m2 = -1.f; int i1 = 0, i2 = 0;
    #pragma unroll
    for (int e = 0; e < E_NUM; e++) {
      float s = sc[e] * inv;
      if (s > m1)      { m2 = m1; i2 = i1; m1 = s; i1 = e; }
      else if (s > m2) { m2 = s; i2 = e; }
    }
    topk_idx[t * 2] = i1; topk_idx[t * 2 + 1] = i2;
    topk_w[t * 2] = m1;  topk_w[t * 2 + 1] = m2;
    atomicAdd(&counts[i1], 1);
    atomicAdd(&counts[i2], 1);
  }
}

// ---------------- 2) 64-aligned padded exclusive scan ----------------
__global__ void offsets_kernel(const int* __restrict__ counts,
                               int* __restrict__ offp, int* __restrict__ cursor)
{
  if (threadIdx.x == 0) {
    int acc = 0;
    #pragma unroll
    for (int e = 0; e < E_NUM; e++) { offp[e] = acc; acc += (counts[e] + 63) & ~63; }
    offp[E_NUM] = acc;
  }
  if (threadIdx.x < E_NUM) cursor[threadIdx.x] = 0;
}

// ---------------- 2b) init padded row arrays ----------------
__global__ __launch_bounds__(256) void initrows_kernel(int* __restrict__ row_token,
                                                       float* __restrict__ row_w) {
  int i = blockIdx.x * 256 + threadIdx.x;
  if (i < RPMAX) { row_token[i] = -1; row_w[i] = 0.f; }
}

// ---------------- 3) scatter tokens into padded per-expert lists ----------------
__global__ __launch_bounds__(256) void scatter_kernel(
    const int* __restrict__ topk_idx, const float* __restrict__ topk_w,
    const int* __restrict__ offp, int* __restrict__ cursor,
    int* __restrict__ row_token, float* __restrict__ row_w)
{
  int t = blockIdx.x * 256 + threadIdx.x;
  if (t >= T_TOK) return;
  #pragma unroll
  for (int k = 0; k < TOPK; k++) {
    int e = topk_idx[t * 2 + k];
    int pos = atomicAdd(&cursor[e], 1);
    int row = offp[e] + pos;
    row_token[row] = t;
    row_w[row] = topk_w[t * 2 + k];
  }
}

// ---------------- 4) GU GEMM: all-streaming FM -> FM inter ----------------
// Block 4 waves. Wave w: 64 rows x 32 cols (of BOTH g and u).
// grid.x = nE * NCB (NCB = Idim/128), grid.y = row-chunk (stride RC*64).
// Epilogue: silu via intra-wave LDS bounce -> FM inter (contiguous 1KB writes).
__global__ __launch_bounds__(256) void gu6_kernel(
    const ushort_t* __restrict__ Af,        // FM [Rp x H]
    const ushort_t* __restrict__ Bgf,       // FM [E*Idim x H]
    const ushort_t* __restrict__ Buf,
    ushort_t* __restrict__ interF,          // FM [Rp x Idim]
    const int* __restrict__ counts,         // null -> dense (total_rows)
    const int* __restrict__ offp,           // null -> 0
    int Idim, int total_rows, int lNCB, int RC)
{
  const int KC = H_DIM / 32;   // 16
  int e  = blockIdx.x >> lNCB;
  int cb = blockIdx.x & ((1 << lNCB) - 1);
  int cntp = counts ? ((counts[e] + 63) & ~63) : total_rows;
  if ((int)(blockIdx.y * 64) >= cntp) return;
  int base = offp ? offp[e] : 0;

  int tid = threadIdx.x, w = tid >> 6, l = tid & 63;
  int fr = l & 15, g = l >> 4;

  size_t ebase = (size_t)e * (Idim >> 4) * KC;
  size_t cgoff = (ebase + (size_t)(cb * 8 + w * 2) * KC) * 64 + l;
  const bf16x8* bg0 = (const bf16x8*)Bgf + cgoff;
  const bf16x8* bg1 = bg0 + (size_t)KC * 64;
  const bf16x8* bu0 = (const bf16x8*)Buf + cgoff;
  const bf16x8* bu1 = bu0 + (size_t)KC * 64;

  __shared__ ushort_t lds[4][64][40];

  int kkg = cb * 4 + w;        // this wave's k-group in down's K space
  int KCd = Idim >> 5;

  for (int n0 = blockIdx.y * 64; n0 < cntp; n0 += RC * 64) {
    int rg0 = (base + n0) >> 4;          // 16-aligned (base 64-aligned)
    const bf16x8* ap = (const bf16x8*)Af + (size_t)rg0 * KC * 64 + l;

    f32x4 accg[4][2] = {}, accu[4][2] = {};
    #pragma unroll 2
    for (int kk = 0; kk < KC; kk++) {
      bf16x8 a[4], bgv[2], buv[2];
      #pragma unroll
      for (int mi = 0; mi < 4; mi++) a[mi] = ap[((size_t)mi * KC + kk) * 64];
      bgv[0] = bg0[(size_t)kk * 64]; bgv[1] = bg1[(size_t)kk * 64];
      buv[0] = bu0[(size_t)kk * 64]; buv[1] = bu1[(size_t)kk * 64];
      #pragma unroll
      for (int mi = 0; mi < 4; mi++) {
        accg[mi][0] = __builtin_amdgcn_mfma_f32_16x16x32_bf16(a[mi], bgv[0], accg[mi][0], 0, 0, 0);
        accg[mi][1] = __builtin_amdgcn_mfma_f32_16x16x32_bf16(a[mi], bgv[1], accg[mi][1], 0, 0, 0);
        accu[mi][0] = __builtin_amdgcn_mfma_f32_16x16x32_bf16(a[mi], buv[0], accu[mi][0], 0, 0, 0);
        accu[mi][1] = __builtin_amdgcn_mfma_f32_16x16x32_bf16(a[mi], buv[1], accu[mi][1], 0, 0, 0);
      }
    }

    // silu(g)*u -> intra-wave LDS bounce -> FM global write
    #pragma unroll
    for (int mi = 0; mi < 4; mi++)
      #pragma unroll
      for (int c = 0; c < 2; c++)
        #pragma unroll
        for (int j = 0; j < 4; j++) {
          float gg = accg[mi][c][j], uu = accu[mi][c][j];
          float s = (gg / (1.f + expf(-gg))) * uu;
          lds[w][mi * 16 + g * 4 + j][c * 16 + fr] = f2bf(s);
        }
    // wave reads back only its own region: no barrier needed
    #pragma unroll
    for (int rg = 0; rg < 4; rg++) {
      bf16x8 v = *(const bf16x8*)&lds[w][rg * 16 + fr][g * 8];
      ((bf16x8*)interF)[((size_t)(rg0 + rg) * KCd + kkg) * 64 + l] = v;
    }
  }
}

// ---------------- 5) down GEMM: all-streaming FM, split-K, atomic/store ------
// Block 4 waves. Wave w: 64 rows x 32 cols. grid.y = rc*NKC + kc.
__global__ __launch_bounds__(256) void down6_kernel(
    const ushort_t* __restrict__ Af,        // FM [Rp x Kdim]
    const ushort_t* __restrict__ Bf,        // FM [E*H x Kdim]
    float* __restrict__ outp,
    const int* __restrict__ row_token,      // null -> identity
    const float* __restrict__ row_w,        // null -> store path (NKC==1)
    const int* __restrict__ counts, const int* __restrict__ offp,
    int Kdim, int total_rows, int lNCB, int RC, int NKC)
{
  int e  = blockIdx.x >> lNCB;
  int cb = blockIdx.x & ((1 << lNCB) - 1);
  int cntp = counts ? ((counts[e] + 63) & ~63) : total_rows;
  int rc = blockIdx.y / NKC, kc = blockIdx.y - rc * NKC;
  if (rc * 64 >= cntp) return;
  int base = offp ? offp[e] : 0;
  int KCd = Kdim >> 5;
  int KCl = KCd / NKC;
  int kk0 = kc * KCl;

  int tid = threadIdx.x, w = tid >> 6, l = tid & 63, fr = l & 15, g = l >> 4;
  size_t cgoff = ((size_t)(e * (H_DIM >> 4) + cb * 8 + w * 2) * KCd + kk0) * 64 + l;
  const bf16x8* b0 = (const bf16x8*)Bf + cgoff;
  const bf16x8* b1 = b0 + (size_t)KCd * 64;
  int c0 = cb * 128 + w * 32;

  for (int n0 = rc * 64; n0 < cntp; n0 += RC * 64) {
    int rg0 = (base + n0) >> 4;
    const bf16x8* ap = (const bf16x8*)Af + ((size_t)rg0 * KCd + kk0) * 64 + l;
    f32x4 acc[4][2] = {};
    #pragma unroll 4
    for (int kk = 0; kk < KCl; kk++) {
      bf16x8 a[4], bv[2];
      #pragma unroll
      for (int mi = 0; mi < 4; mi++) a[mi] = ap[((size_t)mi * KCd + kk) * 64];
      bv[0] = b0[(size_t)kk * 64];
      bv[1] = b1[(size_t)kk * 64];
      #pragma unroll
      for (int mi = 0; mi < 4; mi++) {
        acc[mi][0] = __builtin_amdgcn_mfma_f32_16x16x32_bf16(a[mi], bv[0], acc[mi][0], 0, 0, 0);
        acc[mi][1] = __builtin_amdgcn_mfma_f32_16x16x32_bf16(a[mi], bv[1], acc[mi][1], 0, 0, 0);
      }
    }
    #pragma unroll
    for (int mi = 0; mi < 4; mi++)
      #pragma unroll
      for (int j = 0; j < 4; j++) {
        if (row_w) {
          int grow = base + n0 + mi * 16 + g * 4 + j;
          int tk = row_token[grow];
          if (tk >= 0) {
            float rw = row_w[grow];
            atomicAdd(&outp[(size_t)tk * H_DIM + c0 + fr],      acc[mi][0][j] * rw);
            atomicAdd(&outp[(size_t)tk * H_DIM + c0 + 16 + fr], acc[mi][1][j] * rw);
          }
        } else {
          size_t orow = (size_t)(n0 + mi * 16 + g * 4 + j) * H_DIM;
          outp[orow + c0 + fr]      = acc[mi][0][j];
          outp[orow + c0 + 16 + fr] = acc[mi][1][j];
        }
      }
  }
}

// ---------------- launch ----------------
extern "C" void kernel_launch(void* const* d_in, const int* in_sizes, int n_in,
                              void* d_out, int out_size, void* d_ws, size_t ws_size,
                              hipStream_t stream) {
  const float* x       = (const float*)d_in[0];
  const float* gate_w  = (const float*)d_in[1];
  const float* w_gate  = (const float*)d_in[2];
  const float* w_up    = (const float*)d_in[3];
  const float* w_down  = (const float*)d_in[4];
  const float* sw_gate = (const float*)d_in[5];
  const float* sw_up   = (const float*)d_in[6];
  const float* sw_down = (const float*)d_in[7];
  float* out = (float*)d_out;

  char* ws = (char*)d_ws;
  int*   counts    = (int*)ws;                    // 16 ints
  int*   cursor    = (int*)(ws + 64);             // 16 ints
  int*   offp      = (int*)(ws + 128);            // 17 ints
  int*   topk_idx  = (int*)(ws + 256);            // 4096 ints
  float* topk_w    = (float*)(ws + 16640);        // 4096 f32
  int*   row_token = (int*)(ws + 33024);          // RPMAX ints
  float* row_w     = (float*)(ws + 33024 + RPMAX * 4);
  size_t off = 33024 + (size_t)RPMAX * 8;
  off = (off + 255) & ~(size_t)255;
  ushort_t* xgf  = (ushort_t*)(ws + off); off += (size_t)RPMAX * H_DIM * 2;         // 5 MiB
  ushort_t* xsf  = (ushort_t*)(ws + off); off += (size_t)T_TOK * H_DIM * 2;         // 2 MiB
  ushort_t* wgf  = (ushort_t*)(ws + off); off += (size_t)E_NUM * I_DIM * H_DIM * 2; // 32 MiB
  ushort_t* wuf  = (ushort_t*)(ws + off); off += (size_t)E_NUM * I_DIM * H_DIM * 2; // 32 MiB
  ushort_t* wdf  = (ushort_t*)(ws + off); off += (size_t)E_NUM * H_DIM * I_DIM * 2; // 32 MiB
  ushort_t* swgf = (ushort_t*)(ws + off); off += (size_t)IS_DIM * H_DIM * 2;        // 1 MiB
  ushort_t* swuf = (ushort_t*)(ws + off); off += (size_t)IS_DIM * H_DIM * 2;        // 1 MiB
  ushort_t* swdf = (ushort_t*)(ws + off); off += (size_t)H_DIM * IS_DIM * 2;        // 1 MiB
  ushort_t* interF = (ushort_t*)(ws + off); off += (size_t)RPMAX * I_DIM * 2;       // 20 MiB
  ushort_t* interS = (ushort_t*)(ws + off); off += (size_t)T_TOK * IS_DIM * 2;      // 4 MiB

  hipMemsetAsync(counts, 0, 64, stream);
  gate_kernel<<<T_TOK, 64, 0, stream>>>(x, gate_w, topk_idx, topk_w, counts);
  offsets_kernel<<<1, 64, 0, stream>>>(counts, offp, cursor);
  initrows_kernel<<<RPMAX / 256, 256, 0, stream>>>(row_token, row_w);
  scatter_kernel<<<(T_TOK + 255) / 256, 256, 0, stream>>>(topk_idx, topk_w, offp, cursor,
                                                          row_token, row_w);
  // A-operands into fragment-major bf16
  gatherA_kernel<4><<<640, 256, 0, stream>>>(x, row_token, xgf, RPMAX * H_DIM / 8, H_DIM);
  gatherA_kernel<4><<<512, 256, 0, stream>>>(x, nullptr, xsf, T_TOK * H_DIM / 8, H_DIM);
  // weights into fragment-major bf16
  permw_kernel<4><<<4096, 256, 0, stream>>>(w_gate, wgf, E_NUM * I_DIM * H_DIM / 8, H_DIM);
  permw_kernel<4><<<4096, 256, 0, stream>>>(w_up,   wuf, E_NUM * I_DIM * H_DIM / 8, H_DIM);
  permw_kernel<6><<<4096, 256, 0, stream>>>(w_down, wdf, E_NUM * H_DIM * I_DIM / 8, I_DIM);
  permw_kernel<4><<<256, 256, 0, stream>>>(sw_gate, swgf, IS_DIM * H_DIM / 8, H_DIM);
  permw_kernel<4><<<256, 256, 0, stream>>>(sw_up,   swuf, IS_DIM * H_DIM / 8, H_DIM);
  permw_kernel<5><<<256, 256, 0, stream>>>(sw_down, swdf, H_DIM * IS_DIM / 8, IS_DIM);

  // routed GU: grid (E*16 col-blocks, 8 row-chunks)
  gu6_kernel<<<dim3(E_NUM * 16, 8), 256, 0, stream>>>(
      xgf, wgf, wuf, interF, counts, offp, I_DIM, 0, 4, 8);
  // shared GU: grid (8, 32) dense 2048 rows
  gu6_kernel<<<dim3(8, 32), 256, 0, stream>>>(
      xsf, swgf, swuf, interS, nullptr, nullptr, IS_DIM, T_TOK, 3, 32);
  // shared down first (plain stores initialize out fully)
  down6_kernel<<<dim3(4, 32), 256, 0, stream>>>(
      interS, swdf, out, nullptr, nullptr, nullptr, nullptr, IS_DIM, T_TOK, 2, 32, 1);
  // routed down: split-K=2, weighted atomic accumulation
  down6_kernel<<<dim3(E_NUM * 4, 16), 256, 0, stream>>>(
      interF, wdf, out, row_token, row_w, counts, offp, I_DIM, 0, 2, 8, 2);
}